// Round 1
// baseline (290.996 us; speedup 1.0000x reference)
//
#include <hip/hip_runtime.h>

typedef __bf16 bf16_t;
typedef bf16_t bf16x8 __attribute__((ext_vector_type(8)));
typedef bf16_t bf16x4 __attribute__((ext_vector_type(4)));
typedef float  f32x4  __attribute__((ext_vector_type(4)));

#define DDIM  2048
#define SEQ   2048
#define NH    16
#define HDIM  128
#define BATCH 2
#define MROWS (BATCH * SEQ)  // 4096
#define XEL   ((size_t)MROWS * DDIM)

// ---------------------------------------------------------------- helpers
__device__ __forceinline__ void async_ld16(const bf16_t* g, bf16_t* l) {
  __builtin_amdgcn_global_load_lds(
      (const __attribute__((address_space(1))) void*)g,
      (__attribute__((address_space(3))) void*)l, 16, 0, 0);
}

// ---------------------------------------------------------------- fp32 -> bf16
__global__ void cvt_f32_bf16(const float* __restrict__ in,
                             bf16_t* __restrict__ out, int n) {
  int i = (blockIdx.x * blockDim.x + threadIdx.x) * 4;
  const int stride = gridDim.x * blockDim.x * 4;
  for (; i < n; i += stride) {
    const float4 v = *reinterpret_cast<const float4*>(in + i);
    bf16x4 o;
    o[0] = (bf16_t)v.x; o[1] = (bf16_t)v.y;
    o[2] = (bf16_t)v.z; o[3] = (bf16_t)v.w;
    *reinterpret_cast<bf16x4*>(out + i) = o;
  }
}

// ---------------------------------------------------------------- fused QKV GEMM
// m201 template geometry: BM=256, BN=256, BK=64, 8 waves (2M x 4N), 512 thr.
// Grid 16x24 = 384 blocks (1.5 rounds on 256 CUs; tail is cheaper than the
// previous 256x192 tile's 12-MFMA phases). Wcat = Wq|Wk|Wv rows [6144][2048];
// BN=256 divides 2048 so each block is entirely inside one matrix.
// 8-phase counted-vmcnt schedule (vmcnt(4): A=4 loads, B=4 loads per K-tile):
//   ph1: A(buf1,t1) 4   ph2: B(buf0,t2) 4   ph3: -   ph4: vmcnt(4)
//   ph5: A(buf0,t2) 4   ph6: B(buf1,t3) 4   ph7: -   ph8: vmcnt(4)
// B is reg-cached in each tile's first phase, so its LDS buffer is dead
// afterwards (overwrite at ph2/ph6 is legal, incl. the wrap tail).
__global__ __launch_bounds__(512, 2) void gemm_qkv(
    const bf16_t* __restrict__ Ax, const bf16_t* __restrict__ Wcat,
    const float* __restrict__ bq, const float* __restrict__ bk,
    const float* __restrict__ bv,
    bf16_t* __restrict__ QKVh, float qscale) {
  __shared__ __align__(16) bf16_t sA[2][2][128 * 64];  // 64 KiB
  __shared__ __align__(16) bf16_t sB[2][256 * 64];     // 64 KiB

  const int tid  = threadIdx.x;
  const int lane = tid & 63;
  const int w    = tid >> 6;       // 0..7
  const int wm   = w >> 2;         // 0..1
  const int wn   = w & 3;          // 0..3
  const int lg   = lane >> 4;
  const int lr   = lane & 15;

  const int bid = blockIdx.x;                    // 0..383
  const int l   = (bid & 7) * 48 + (bid >> 3);   // XCD swizzle (384%8==0)
  const int tm  = l & 15;                        // 0..15
  const int tn  = l >> 4;                        // 0..23
  const int row0  = tm * 256;
  const int ncol0 = tn * 256;

  // stage: LDS linear dest, source pre-swizzled (chunk ch^(r&7))
  auto stA = [&](int buf, int ha, int kt) {
#pragma unroll
    for (int L = 0; L < 2; ++L) {
      const int c = L * 512 + tid, r = c >> 3, ch = c & 7;
      async_ld16(Ax + (size_t)(row0 + ha * 128 + r) * DDIM + kt * 64 +
                     ((ch ^ (r & 7)) * 8),
                 &sA[buf][ha][c * 8]);
    }
  };
  auto stB = [&](int buf, int kt) {
#pragma unroll
    for (int L = 0; L < 4; ++L) {
      const int c = L * 512 + tid, r = c >> 3, ch = c & 7;   // r 0..255
      async_ld16(Wcat + (size_t)(ncol0 + r) * DDIM + kt * 64 +
                     ((ch ^ (r & 7)) * 8),
                 &sB[buf][c * 8]);
    }
  };
  auto ldA = [&](int buf, int mf, int k) {
    const int row = mf * 16 + lr;                 // within half wm
    const int ch  = (k * 4 + lg) ^ (row & 7);
    return *reinterpret_cast<const bf16x8*>(&sA[buf][wm][row * 64 + ch * 8]);
  };
  auto ldB = [&](int buf, int nf, int k) {
    const int row = wn * 64 + nf * 16 + lr;       // 0..255
    const int ch  = (k * 4 + lg) ^ (row & 7);
    return *reinterpret_cast<const bf16x8*>(&sB[buf][row * 64 + ch * 8]);
  };

  f32x4  acc[8][4] = {};
  bf16x8 bfr[4][2];

#define GPH(BUF, Q, LOADB, STAGE_STMT, VMW)                                   \
  {                                                                           \
    bf16x8 a00 = ldA(BUF, 2 * (Q), 0), a01 = ldA(BUF, 2 * (Q), 1);            \
    bf16x8 a10 = ldA(BUF, 2 * (Q) + 1, 0), a11 = ldA(BUF, 2 * (Q) + 1, 1);    \
    if (LOADB) {                                                              \
      _Pragma("unroll") for (int nf = 0; nf < 4; ++nf) {                      \
        bfr[nf][0] = ldB(BUF, nf, 0);                                         \
        bfr[nf][1] = ldB(BUF, nf, 1);                                         \
      }                                                                       \
    }                                                                         \
    STAGE_STMT;                                                               \
    if (VMW) asm volatile("s_waitcnt vmcnt(4)" ::: "memory");                 \
    __builtin_amdgcn_s_barrier();                                             \
    asm volatile("s_waitcnt lgkmcnt(0)" ::: "memory");                        \
    __builtin_amdgcn_sched_barrier(0);                                        \
    __builtin_amdgcn_s_setprio(1);                                            \
    _Pragma("unroll") for (int k = 0; k < 2; ++k) {                           \
      const bf16x8 A0 = k ? a01 : a00;                                        \
      const bf16x8 A1 = k ? a11 : a10;                                        \
      _Pragma("unroll") for (int nf = 0; nf < 4; ++nf) {                      \
        acc[2 * (Q)][nf] = __builtin_amdgcn_mfma_f32_16x16x32_bf16(           \
            A0, bfr[nf][k], acc[2 * (Q)][nf], 0, 0, 0);                       \
        acc[2 * (Q) + 1][nf] = __builtin_amdgcn_mfma_f32_16x16x32_bf16(       \
            A1, bfr[nf][k], acc[2 * (Q) + 1][nf], 0, 0, 0);                   \
      }                                                                       \
    }                                                                         \
    __builtin_amdgcn_s_setprio(0);                                            \
    __builtin_amdgcn_s_barrier();                                             \
  }

  // prologue: buf0 complete (A 4 + B 4) + B(buf1,t1) 4 in flight
  stA(0, 0, 0); stA(0, 1, 0);
  stB(0, 0);
  stB(1, 1);
  asm volatile("s_waitcnt vmcnt(4)" ::: "memory");
  __builtin_amdgcn_s_barrier();

  for (int i = 0; i < 16; ++i) {
    const int t1 = (2 * i + 1) & 31;
    const int t2 = (2 * i + 2) & 31;   // wraps on last iter (harmless)
    const int t3 = (2 * i + 3) & 31;
    GPH(0, 0, true,  { stA(1, 0, t1); stA(1, 1, t1); }, 0)
    GPH(0, 1, false, { stB(0, t2); },                   0)
    GPH(0, 2, false, {},                                0)
    GPH(0, 3, false, {},                                1)
    GPH(1, 0, true,  { stA(0, 0, t2); stA(0, 1, t2); }, 0)
    GPH(1, 1, false, { stB(1, t3); },                   0)
    GPH(1, 2, false, {},                                0)
    GPH(1, 3, false, {},                                1)
  }
#undef GPH
  asm volatile("s_waitcnt vmcnt(0)" ::: "memory");

  // epilogue -> head layout [B,H,S,HD]; whole block lies inside one matrix
  const int matb = tn >> 3;                       // 0=Q 1=K 2=V (block-uniform)
  const float* bb = (matb == 0) ? bq : (matb == 1) ? bk : bv;
  const float sc = (matb == 0) ? qscale : 1.0f;
  bf16_t* outb = QKVh + (size_t)matb * XEL;
#pragma unroll
  for (int mf = 0; mf < 8; ++mf) {
    const int rr0 = row0 + wm * 128 + mf * 16 + lg * 4;
#pragma unroll
    for (int nf = 0; nf < 4; ++nf) {
      const int c2 = (tn & 7) * 256 + wn * 64 + nf * 16 + lr;  // 0..2047
      const float bs = bb[c2];
      const int h = c2 >> 7, hd = c2 & (HDIM - 1);
#pragma unroll
      for (int r = 0; r < 4; ++r) {
        const int rr = rr0 + r;
        const int b = rr >> 11, s = rr & (SEQ - 1);
        outb[(((size_t)(b * NH + h)) * SEQ + s) * HDIM + hd] =
            (bf16_t)((acc[mf][nf][r] + bs) * sc);
      }
    }
  }
}

// ---------------------------------------------------------------- GEMM  C = (A @ B^T + bias) * scale
template <int OUTMODE>
__global__ __launch_bounds__(256) void gemm_bt(
    const bf16_t* __restrict__ A, const bf16_t* __restrict__ Bw,
    const float* __restrict__ bias, void* __restrict__ outp,
    int M, int N, int K, float scale) {
  __shared__ __align__(16) bf16_t sA[2][128 * 32];
  __shared__ __align__(16) bf16_t sB[2][128 * 32];

  const int tid  = threadIdx.x;
  const int lane = tid & 63;
  const int w    = tid >> 6;
  const int wm   = w >> 1;
  const int wn   = w & 1;
  const int lg   = lane >> 4;
  const int lr   = lane & 15;
  const int row0 = blockIdx.y * 128;
  const int col0 = blockIdx.x * 128;

  const int srow = tid >> 2;        // 0..63
  const int scol = (tid & 3) * 8;   // 0,8,16,24

  const bf16_t* gA = A  + (size_t)(row0 + srow) * K + scol;
  const bf16_t* gB = Bw + (size_t)(col0 + srow) * K + scol;

  f32x4 acc[4][4] = {};

  auto stage = [&](int buf, int k0) {
    async_ld16(gA + k0,                  &sA[buf][tid * 8]);
    async_ld16(gA + 64 * (size_t)K + k0, &sA[buf][(256 + tid) * 8]);
    async_ld16(gB + k0,                  &sB[buf][tid * 8]);
    async_ld16(gB + 64 * (size_t)K + k0, &sB[buf][(256 + tid) * 8]);
  };

  stage(0, 0);
  __syncthreads();

  int cur = 0;
  const int NT = K / 32;
  for (int t = 0; t < NT; ++t) {
    if (t + 1 < NT) stage(cur ^ 1, (t + 1) * 32);
    bf16x8 af[4], bfr[4];
#pragma unroll
    for (int i = 0; i < 4; ++i) {
      af[i]  = *reinterpret_cast<const bf16x8*>(
          &sA[cur][(wm * 64 + i * 16 + lr) * 32 + lg * 8]);
      bfr[i] = *reinterpret_cast<const bf16x8*>(
          &sB[cur][(wn * 64 + i * 16 + lr) * 32 + lg * 8]);
    }
#pragma unroll
    for (int i = 0; i < 4; ++i)
#pragma unroll
      for (int j = 0; j < 4; ++j)
        acc[i][j] = __builtin_amdgcn_mfma_f32_16x16x32_bf16(
            af[i], bfr[j], acc[i][j], 0, 0, 0);
    __syncthreads();
    cur ^= 1;
  }

#pragma unroll
  for (int i = 0; i < 4; ++i) {
    const int rowb = row0 + wm * 64 + i * 16 + lg * 4;
#pragma unroll
    for (int j = 0; j < 4; ++j) {
      const int col = col0 + wn * 64 + j * 16 + lr;
      const float bs = bias[col];
#pragma unroll
      for (int r = 0; r < 4; ++r) {
        const float v = (acc[i][j][r] + bs) * scale;
        const int rr = rowb + r;
        if (OUTMODE == 2) {
          ((float*)outp)[(size_t)rr * N + col] = v;
        } else {
          const int b  = rr >> 11;          // / SEQ
          const int s  = rr & (SEQ - 1);
          const int h  = col >> 7;          // / HDIM
          const int hd = col & (HDIM - 1);
          ((bf16_t*)outp)[(((size_t)(b * NH + h)) * SEQ + s) * HDIM + hd] =
              (bf16_t)v;
        }
      }
    }
  }
}

// ---------------------------------------------------------------- V transpose per head
__global__ __launch_bounds__(256) void transpose_v(
    const bf16_t* __restrict__ Vp, bf16_t* __restrict__ Vt) {
  __shared__ __align__(16) bf16_t tt[64][72];
  const int bh = blockIdx.z;
  const int s0 = blockIdx.x * 64;
  const int d0 = blockIdx.y * 64;
  const int t  = threadIdx.x;
#pragma unroll
  for (int c = 0; c < 2; ++c) {
    const int r   = (c * 256 + t) >> 3;   // 0..63
    const int col = (t & 7) * 8;
    bf16x8 v = *reinterpret_cast<const bf16x8*>(
        Vp + ((size_t)bh * SEQ + s0 + r) * HDIM + d0 + col);
    *reinterpret_cast<bf16x8*>(&tt[r][col]) = v;
  }
  __syncthreads();
#pragma unroll
  for (int c = 0; c < 2; ++c) {
    const int dr = (c * 256 + t) >> 3;    // 0..63 (d row)
    const int sc = (t & 7) * 8;           // s chunk
    bf16x8 o;
#pragma unroll
    for (int i = 0; i < 8; ++i) o[i] = tt[sc + i][dr];
    *reinterpret_cast<bf16x8*>(
        Vt + ((size_t)bh * HDIM + d0 + dr) * SEQ + s0 + sc) = o;
  }
}

// ---------------------------------------------------------------- flash attention
// Q (pre-scaled by log2e/sqrt(HD)), K [BH][SEQ][HD], Vt [BH][HD][SEQ] -> merged
// R4 structure (global_load_lds staging, 2 barriers/tile, exp2 softmax with
// no online max, row-sum via ones-MFMA) + XCD swizzle.
__global__ __launch_bounds__(256) void attn_fwd(
    const bf16_t* __restrict__ Q, const bf16_t* __restrict__ K,
    const bf16_t* __restrict__ Vt, bf16_t* __restrict__ out) {
  __shared__ __align__(16) bf16_t sK[64 * 128];   // 16 KB, swizzled chunks
  __shared__ __align__(16) bf16_t sV[128 * 64];   // 16 KB, swizzled chunks
  __shared__ __align__(16) bf16_t sP[4][32][72];  // 18.4 KB, padded

  const int tid  = threadIdx.x;
  const int lane = tid & 63;
  const int w    = tid >> 6;
  const int lg   = lane >> 4;
  const int lr   = lane & 15;

  const int bid     = blockIdx.x;                 // 0..511
  const int logical = (bid & 7) * 64 + (bid >> 3);
  const int bh      = logical >> 4;               // b*H + h
  const int q0      = (logical & 15) * 128;
  const int qw      = q0 + w * 32;

  const bf16_t* Kb = K  + (size_t)bh * SEQ * HDIM;
  const bf16_t* Vb = Vt + (size_t)bh * HDIM * SEQ;

  bf16x8 qf[2][4];
#pragma unroll
  for (int mf = 0; mf < 2; ++mf) {
    const bf16_t* qbase = Q + ((size_t)bh * SEQ + qw + mf * 16 + lr) * HDIM;
#pragma unroll
    for (int kc = 0; kc < 4; ++kc)
      qf[mf][kc] = *reinterpret_cast<const bf16x8*>(qbase + kc * 32 + lg * 8);
  }

  bf16x8 onesf;
#pragma unroll
  for (int i = 0; i < 8; ++i) onesf[i] = (bf16_t)1.0f;

  f32x4 o[2][8] = {};
  f32x4 o1[2] = {};   // row-sum accumulators

  for (int kv0 = 0; kv0 < SEQ; kv0 += 64) {
    __syncthreads();
#pragma unroll
    for (int p = 0; p < 4; ++p) {
      const int slot = p * 256 + tid;          // 0..1023 (16B chunks)
      const int kr = slot >> 4, kc = slot & 15;
      async_ld16(Kb + ((size_t)(kv0 + kr)) * HDIM + ((kc ^ (kr & 7)) * 8),
                 sK + slot * 8);
      const int vr = slot >> 3, vc = slot & 7;
      async_ld16(Vb + (size_t)vr * SEQ + kv0 + ((vc ^ (vr & 7)) * 8),
                 sV + slot * 8);
    }
    __syncthreads();

    // ---- QK^T
    f32x4 s[2][4] = {};
    __builtin_amdgcn_s_setprio(1);
#pragma unroll
    for (int kc = 0; kc < 4; ++kc) {
#pragma unroll
      for (int cb = 0; cb < 4; ++cb) {
        const int r  = cb * 16 + lr;
        const int ch = kc * 4 + lg;
        bf16x8 kf = *reinterpret_cast<const bf16x8*>(
            sK + r * 128 + ((ch ^ (r & 7)) * 8));
        s[0][cb] = __builtin_amdgcn_mfma_f32_16x16x32_bf16(qf[0][kc], kf, s[0][cb], 0, 0, 0);
        s[1][cb] = __builtin_amdgcn_mfma_f32_16x16x32_bf16(qf[1][kc], kf, s[1][cb], 0, 0, 0);
      }
    }
    __builtin_amdgcn_s_setprio(0);

    // ---- p = exp2(s)
#pragma unroll
    for (int mf = 0; mf < 2; ++mf)
#pragma unroll
      for (int r = 0; r < 4; ++r)
#pragma unroll
        for (int cb = 0; cb < 4; ++cb) {
          const float p = __builtin_amdgcn_exp2f(s[mf][cb][r]);
          sP[w][mf * 16 + lg * 4 + r][cb * 16 + lr] = (bf16_t)p;
        }

    asm volatile("s_waitcnt lgkmcnt(0)" ::: "memory");

    // ---- PV + row-sum
    __builtin_amdgcn_s_setprio(1);
#pragma unroll
    for (int ks = 0; ks < 2; ++ks) {
      bf16x8 pf0 = *reinterpret_cast<const bf16x8*>(&sP[w][lr][ks * 32 + lg * 8]);
      bf16x8 pf1 = *reinterpret_cast<const bf16x8*>(&sP[w][16 + lr][ks * 32 + lg * 8]);
      o1[0] = __builtin_amdgcn_mfma_f32_16x16x32_bf16(pf0, onesf, o1[0], 0, 0, 0);
      o1[1] = __builtin_amdgcn_mfma_f32_16x16x32_bf16(pf1, onesf, o1[1], 0, 0, 0);
#pragma unroll
      for (int ob = 0; ob < 8; ++ob) {
        const int r  = ob * 16 + lr;
        const int ch = ks * 4 + lg;
        bf16x8 vf = *reinterpret_cast<const bf16x8*>(
            sV + r * 64 + ((ch ^ (r & 7)) * 8));
        o[0][ob] = __builtin_amdgcn_mfma_f32_16x16x32_bf16(pf0, vf, o[0][ob], 0, 0, 0);
        o[1][ob] = __builtin_amdgcn_mfma_f32_16x16x32_bf16(pf1, vf, o[1][ob], 0, 0, 0);
      }
    }
    __builtin_amdgcn_s_setprio(0);
  }

  // ---- epilogue
  const int b = bh >> 4, h = bh & 15;
#pragma unroll
  for (int mf = 0; mf < 2; ++mf) {
#pragma unroll
    for (int r = 0; r < 4; ++r) {
      const float inv_l = 1.0f / o1[mf][r];
      const int row = qw + mf * 16 + lg * 4 + r;
      bf16_t* obase = out + ((size_t)b * SEQ + row) * DDIM + h * HDIM;
#pragma unroll
      for (int ob = 0; ob < 8; ++ob)
        obase[ob * 16 + lr] = (bf16_t)(o[mf][ob][r] * inv_l);
    }
  }
}

// ---------------------------------------------------------------- launch
extern "C" void kernel_launch(void* const* d_in, const int* in_sizes, int n_in,
                              void* d_out, int out_size, void* d_ws,
                              size_t ws_size, hipStream_t stream) {
  const float* x  = (const float*)d_in[0];
  const float* Wq = (const float*)d_in[1];
  const float* bq = (const float*)d_in[2];
  const float* Wk = (const float*)d_in[3];
  const float* bk = (const float*)d_in[4];
  const float* Wv = (const float*)d_in[5];
  const float* bv = (const float*)d_in[6];
  const float* Wo = (const float*)d_in[7];
  const float* bo = (const float*)d_in[8];

  bf16_t* ws = (bf16_t*)d_ws;
  const size_t XE = XEL;                   // 8388608
  const size_t WE = (size_t)DDIM * DDIM;   // 4194304
  bf16_t* xb  = ws;          // reused as `merged` after QKV GEMM
  bf16_t* wqb = ws + XE;     // wqb|wkb|wvb contiguous = Wcat [6144][2048]
  bf16_t* wkb = wqb + WE;
  bf16_t* wvb = wkb + WE;
  bf16_t* wob = wvb + WE;
  bf16_t* Qh  = wob + WE;    // Qh|Kh|Vh contiguous
  bf16_t* Kh  = Qh + XE;
  bf16_t* Vh  = Kh + XE;
  bf16_t* Vt  = Vh + XE;
  bf16_t* merged = xb;

  cvt_f32_bf16<<<4096, 256, 0, stream>>>(x, xb, (int)XE);
  cvt_f32_bf16<<<2048, 256, 0, stream>>>(Wq, wqb, (int)WE);
  cvt_f32_bf16<<<2048, 256, 0, stream>>>(Wk, wkb, (int)WE);
  cvt_f32_bf16<<<2048, 256, 0, stream>>>(Wv, wvb, (int)WE);
  cvt_f32_bf16<<<2048, 256, 0, stream>>>(Wo, wob, (int)WE);

  // scale = (1/sqrt(HD)) * log2(e), folded into Q so attn uses exp2 directly
  const float qscale = 0.12751744520778695f;

  gemm_qkv<<<384, 512, 0, stream>>>(xb, wqb, bq, bk, bv, Qh, qscale);

  transpose_v<<<dim3(SEQ / 64, HDIM / 64, BATCH * NH), 256, 0, stream>>>(Vh, Vt);

  attn_fwd<<<512, 256, 0, stream>>>(Qh, Kh, Vt, merged);

  dim3 gg(DDIM / 128, MROWS / 128);
  gemm_bt<2><<<gg, 256, 0, stream>>>(merged, wob, bo, d_out, MROWS, DDIM, DDIM, 1.0f);
}

// Round 2
// 251.951 us; speedup vs baseline: 1.1550x; 1.1550x over previous
//
#include <hip/hip_runtime.h>

typedef __bf16 bf16_t;
typedef bf16_t bf16x8 __attribute__((ext_vector_type(8)));
typedef bf16_t bf16x4 __attribute__((ext_vector_type(4)));
typedef float  f32x4  __attribute__((ext_vector_type(4)));

#define DDIM  2048
#define SEQ   2048
#define NH    16
#define HDIM  128
#define BATCH 2
#define MROWS (BATCH * SEQ)  // 4096
#define XEL   ((size_t)MROWS * DDIM)

// ---------------------------------------------------------------- helpers
__device__ __forceinline__ void async_ld16(const bf16_t* g, bf16_t* l) {
  __builtin_amdgcn_global_load_lds(
      (const __attribute__((address_space(1))) void*)g,
      (__attribute__((address_space(3))) void*)l, 16, 0, 0);
}

// ---------------------------------------------------------------- fp32 -> bf16
__global__ void cvt_f32_bf16(const float* __restrict__ in,
                             bf16_t* __restrict__ out, int n) {
  int i = (blockIdx.x * blockDim.x + threadIdx.x) * 4;
  const int stride = gridDim.x * blockDim.x * 4;
  for (; i < n; i += stride) {
    const float4 v = *reinterpret_cast<const float4*>(in + i);
    bf16x4 o;
    o[0] = (bf16_t)v.x; o[1] = (bf16_t)v.y;
    o[2] = (bf16_t)v.z; o[3] = (bf16_t)v.w;
    *reinterpret_cast<bf16x4*>(out + i) = o;
  }
}

// ---------------------------------------------------------------- fused QKV GEMM
// BM=256, BN=192, BK=64, 8 waves (2M x 4N), 512 thr. Grid 512 = exactly 2
// rounds on 256 CUs (equal blocks + 1 block/CU => rounds must pack evenly;
// the 384-block 256x256 variant cost 2 rounds anyway = 25% idle).
//
// Deep-prefetch / sparse-barrier schedule (round-2 change): all 22 ds_reads
// of a half-tile (16 A-frag + 6 B-frag) are issued at the half-tile top and
// drained with counted lgkmcnt(12/8/4/0) in front of the 4 MFMA phases.
// Only 4 s_barriers per 8 phases (ph1-mid, ph4-end, ph5-mid, ph8-end) vs 16
// before: waves may skew so one wave's MFMA overlaps another's LDS drain.
// sched_barrier(0) pins the read-group order so the counted waits are valid,
// and fences MFMA from hoisting above the asm lgkmcnt (reg-only ops ignore
// the "memory" clobber).
// vmcnt FIFO check (3 B-loads + 4 A-loads per tile, steady state):
//   at ph4 wait: [B-t1:3][A-t1:4][B-t2:3] -> vmcnt(3) completes B-t1+A-t1,
//   exactly what ph5's buf1 reads need; symmetric at ph8.
__global__ __launch_bounds__(512, 2) void gemm_qkv(
    const bf16_t* __restrict__ Ax, const bf16_t* __restrict__ Wcat,
    const float* __restrict__ bq, const float* __restrict__ bk,
    const float* __restrict__ bv,
    bf16_t* __restrict__ QKVh, float qscale) {
  __shared__ __align__(16) bf16_t sA[2][2][128 * 64];  // 64 KiB
  __shared__ __align__(16) bf16_t sB[2][192 * 64];     // 48 KiB

  const int tid  = threadIdx.x;
  const int lane = tid & 63;
  const int w    = tid >> 6;       // 0..7
  const int wm   = w >> 2;         // 0..1
  const int wn   = w & 3;          // 0..3
  const int lg   = lane >> 4;
  const int lr   = lane & 15;

  const int bid = blockIdx.x;                    // 0..511
  const int l   = (bid & 7) * 64 + (bid >> 3);   // XCD swizzle (512%8==0)
  const int tm  = l & 15;                        // 0..15
  const int tn  = l >> 4;                        // 0..31
  const int row0  = tm * 256;
  const int ncol0 = tn * 192;

  // stage: LDS linear dest, source pre-swizzled (chunk ch^(r&7))
  auto stA = [&](int buf, int ha, int kt) {
#pragma unroll
    for (int L = 0; L < 2; ++L) {
      const int c = L * 512 + tid, r = c >> 3, ch = c & 7;
      async_ld16(Ax + (size_t)(row0 + ha * 128 + r) * DDIM + kt * 64 +
                     ((ch ^ (r & 7)) * 8),
                 &sA[buf][ha][c * 8]);
    }
  };
  auto stB = [&](int buf, int kt) {
#pragma unroll
    for (int L = 0; L < 3; ++L) {
      const int c = L * 512 + tid, r = c >> 3, ch = c & 7;   // r 0..191
      async_ld16(Wcat + (size_t)(ncol0 + r) * DDIM + kt * 64 +
                     ((ch ^ (r & 7)) * 8),
                 &sB[buf][c * 8]);
    }
  };
  auto ldA = [&](int buf, int mf, int k) {
    const int row = mf * 16 + lr;                 // within half wm
    const int ch  = (k * 4 + lg) ^ (row & 7);
    return *reinterpret_cast<const bf16x8*>(&sA[buf][wm][row * 64 + ch * 8]);
  };
  auto ldB = [&](int buf, int nf, int k) {
    const int row = wn * 48 + nf * 16 + lr;       // 0..191
    const int ch  = (k * 4 + lg) ^ (row & 7);
    return *reinterpret_cast<const bf16x8*>(&sB[buf][row * 64 + ch * 8]);
  };

  f32x4  acc[8][3] = {};
  bf16x8 a[8][2];     // A-frags for the whole half-tile (4 phases)
  bf16x8 bfr[3][2];   // B-frags (reg-cached for the tile)

#define MFMA_PH(Q)                                                            \
  __builtin_amdgcn_s_setprio(1);                                              \
  _Pragma("unroll") for (int k = 0; k < 2; ++k) {                             \
    _Pragma("unroll") for (int nf = 0; nf < 3; ++nf) {                        \
      acc[2 * (Q)][nf] = __builtin_amdgcn_mfma_f32_16x16x32_bf16(             \
          a[2 * (Q)][k], bfr[nf][k], acc[2 * (Q)][nf], 0, 0, 0);              \
      acc[2 * (Q) + 1][nf] = __builtin_amdgcn_mfma_f32_16x16x32_bf16(         \
          a[2 * (Q) + 1][k], bfr[nf][k], acc[2 * (Q) + 1][nf], 0, 0, 0);      \
    }                                                                         \
  }                                                                           \
  __builtin_amdgcn_s_setprio(0);

  // one half-tile = 4 MFMA phases over buf BUF; ST1/ST2 are the stage stmts
#define HALF(BUF, ST1, ST2)                                                   \
  {                                                                           \
    /* reads needed by ph1 (Q0 A-frags + all B-frags): first 10 in order */   \
    a[0][0] = ldA(BUF, 0, 0); a[0][1] = ldA(BUF, 0, 1);                       \
    a[1][0] = ldA(BUF, 1, 0); a[1][1] = ldA(BUF, 1, 1);                       \
    _Pragma("unroll") for (int nf = 0; nf < 3; ++nf) {                        \
      bfr[nf][0] = ldB(BUF, nf, 0); bfr[nf][1] = ldB(BUF, nf, 1);             \
    }                                                                         \
    __builtin_amdgcn_sched_barrier(0);                                        \
    a[2][0] = ldA(BUF, 2, 0); a[2][1] = ldA(BUF, 2, 1);                       \
    a[3][0] = ldA(BUF, 3, 0); a[3][1] = ldA(BUF, 3, 1);                       \
    __builtin_amdgcn_sched_barrier(0);                                        \
    a[4][0] = ldA(BUF, 4, 0); a[4][1] = ldA(BUF, 4, 1);                       \
    a[5][0] = ldA(BUF, 5, 0); a[5][1] = ldA(BUF, 5, 1);                       \
    __builtin_amdgcn_sched_barrier(0);                                        \
    a[6][0] = ldA(BUF, 6, 0); a[6][1] = ldA(BUF, 6, 1);                       \
    a[7][0] = ldA(BUF, 7, 0); a[7][1] = ldA(BUF, 7, 1);                       \
    ST1;                                                                      \
    asm volatile("s_waitcnt lgkmcnt(12)" ::: "memory");                       \
    __builtin_amdgcn_sched_barrier(0);                                        \
    __builtin_amdgcn_s_barrier();                                             \
    MFMA_PH(0)                                                                \
    ST2;                                                                      \
    asm volatile("s_waitcnt lgkmcnt(8)" ::: "memory");                        \
    __builtin_amdgcn_sched_barrier(0);                                        \
    MFMA_PH(1)                                                                \
    asm volatile("s_waitcnt lgkmcnt(4)" ::: "memory");                        \
    __builtin_amdgcn_sched_barrier(0);                                        \
    MFMA_PH(2)                                                                \
    asm volatile("s_waitcnt lgkmcnt(0)" ::: "memory");                        \
    __builtin_amdgcn_sched_barrier(0);                                        \
    MFMA_PH(3)                                                                \
    asm volatile("s_waitcnt vmcnt(3)" ::: "memory");                          \
    __builtin_amdgcn_s_barrier();                                             \
  }

  // prologue: buf0 complete (A 4 + B 3) + B(buf1,t1) 3 in flight
  stA(0, 0, 0); stA(0, 1, 0);
  stB(0, 0);
  stB(1, 1);
  asm volatile("s_waitcnt vmcnt(3)" ::: "memory");
  __builtin_amdgcn_s_barrier();

  for (int i = 0; i < 16; ++i) {
    const int t1 = (2 * i + 1) & 31;
    const int t2 = (2 * i + 2) & 31;   // wraps on last iter (harmless)
    const int t3 = (2 * i + 3) & 31;
    HALF(0, { stA(1, 0, t1); stA(1, 1, t1); }, { stB(0, t2); })
    HALF(1, { stA(0, 0, t2); stA(0, 1, t2); }, { stB(1, t3); })
  }
#undef HALF
#undef MFMA_PH
  asm volatile("s_waitcnt vmcnt(0)" ::: "memory");

  // epilogue -> head layout [B,H,S,HD]; per-column matrix select (192-col
  // tiles cross the Q/K/V boundaries)
#pragma unroll
  for (int mf = 0; mf < 8; ++mf) {
    const int rr0 = row0 + wm * 128 + mf * 16 + lg * 4;
#pragma unroll
    for (int nf = 0; nf < 3; ++nf) {
      const int col = ncol0 + wn * 48 + nf * 16 + lr;   // 0..6143
      const int mat = col >> 11;
      const int c2  = col & (DDIM - 1);
      const float bs = ((mat == 0) ? bq : (mat == 1) ? bk : bv)[c2];
      const float sc = (mat == 0) ? qscale : 1.0f;
      const int h = c2 >> 7, hd = c2 & (HDIM - 1);
      bf16_t* outb = QKVh + (size_t)mat * XEL;
#pragma unroll
      for (int r = 0; r < 4; ++r) {
        const int rr = rr0 + r;
        const int b = rr >> 11, s = rr & (SEQ - 1);
        outb[(((size_t)(b * NH + h)) * SEQ + s) * HDIM + hd] =
            (bf16_t)((acc[mf][nf][r] + bs) * sc);
      }
    }
  }
}

// ---------------------------------------------------------------- GEMM  C = (A @ B^T + bias) * scale
template <int OUTMODE>
__global__ __launch_bounds__(256) void gemm_bt(
    const bf16_t* __restrict__ A, const bf16_t* __restrict__ Bw,
    const float* __restrict__ bias, void* __restrict__ outp,
    int M, int N, int K, float scale) {
  __shared__ __align__(16) bf16_t sA[2][128 * 32];
  __shared__ __align__(16) bf16_t sB[2][128 * 32];

  const int tid  = threadIdx.x;
  const int lane = tid & 63;
  const int w    = tid >> 6;
  const int wm   = w >> 1;
  const int wn   = w & 1;
  const int lg   = lane >> 4;
  const int lr   = lane & 15;
  const int row0 = blockIdx.y * 128;
  const int col0 = blockIdx.x * 128;

  const int srow = tid >> 2;        // 0..63
  const int scol = (tid & 3) * 8;   // 0,8,16,24

  const bf16_t* gA = A  + (size_t)(row0 + srow) * K + scol;
  const bf16_t* gB = Bw + (size_t)(col0 + srow) * K + scol;

  f32x4 acc[4][4] = {};

  auto stage = [&](int buf, int k0) {
    async_ld16(gA + k0,                  &sA[buf][tid * 8]);
    async_ld16(gA + 64 * (size_t)K + k0, &sA[buf][(256 + tid) * 8]);
    async_ld16(gB + k0,                  &sB[buf][tid * 8]);
    async_ld16(gB + 64 * (size_t)K + k0, &sB[buf][(256 + tid) * 8]);
  };

  stage(0, 0);
  __syncthreads();

  int cur = 0;
  const int NT = K / 32;
  for (int t = 0; t < NT; ++t) {
    if (t + 1 < NT) stage(cur ^ 1, (t + 1) * 32);
    bf16x8 af[4], bfr[4];
#pragma unroll
    for (int i = 0; i < 4; ++i) {
      af[i]  = *reinterpret_cast<const bf16x8*>(
          &sA[cur][(wm * 64 + i * 16 + lr) * 32 + lg * 8]);
      bfr[i] = *reinterpret_cast<const bf16x8*>(
          &sB[cur][(wn * 64 + i * 16 + lr) * 32 + lg * 8]);
    }
#pragma unroll
    for (int i = 0; i < 4; ++i)
#pragma unroll
      for (int j = 0; j < 4; ++j)
        acc[i][j] = __builtin_amdgcn_mfma_f32_16x16x32_bf16(
            af[i], bfr[j], acc[i][j], 0, 0, 0);
    __syncthreads();
    cur ^= 1;
  }

#pragma unroll
  for (int i = 0; i < 4; ++i) {
    const int rowb = row0 + wm * 64 + i * 16 + lg * 4;
#pragma unroll
    for (int j = 0; j < 4; ++j) {
      const int col = col0 + wn * 64 + j * 16 + lr;
      const float bs = bias[col];
#pragma unroll
      for (int r = 0; r < 4; ++r) {
        const float v = (acc[i][j][r] + bs) * scale;
        const int rr = rowb + r;
        if (OUTMODE == 2) {
          ((float*)outp)[(size_t)rr * N + col] = v;
        } else {
          const int b  = rr >> 11;          // / SEQ
          const int s  = rr & (SEQ - 1);
          const int h  = col >> 7;          // / HDIM
          const int hd = col & (HDIM - 1);
          ((bf16_t*)outp)[(((size_t)(b * NH + h)) * SEQ + s) * HDIM + hd] =
              (bf16_t)v;
        }
      }
    }
  }
}

// ---------------------------------------------------------------- V transpose per head
__global__ __launch_bounds__(256) void transpose_v(
    const bf16_t* __restrict__ Vp, bf16_t* __restrict__ Vt) {
  __shared__ __align__(16) bf16_t tt[64][72];
  const int bh = blockIdx.z;
  const int s0 = blockIdx.x * 64;
  const int d0 = blockIdx.y * 64;
  const int t  = threadIdx.x;
#pragma unroll
  for (int c = 0; c < 2; ++c) {
    const int r   = (c * 256 + t) >> 3;   // 0..63
    const int col = (t & 7) * 8;
    bf16x8 v = *reinterpret_cast<const bf16x8*>(
        Vp + ((size_t)bh * SEQ + s0 + r) * HDIM + d0 + col);
    *reinterpret_cast<bf16x8*>(&tt[r][col]) = v;
  }
  __syncthreads();
#pragma unroll
  for (int c = 0; c < 2; ++c) {
    const int dr = (c * 256 + t) >> 3;    // 0..63 (d row)
    const int sc = (t & 7) * 8;           // s chunk
    bf16x8 o;
#pragma unroll
    for (int i = 0; i < 8; ++i) o[i] = tt[sc + i][dr];
    *reinterpret_cast<bf16x8*>(
        Vt + ((size_t)bh * HDIM + d0 + dr) * SEQ + s0 + sc) = o;
  }
}

// ---------------------------------------------------------------- flash attention
// Q (pre-scaled by log2e/sqrt(HD)), K [BH][SEQ][HD], Vt [BH][HD][SEQ] -> merged
// R4 structure (global_load_lds staging, 2 barriers/tile, exp2 softmax with
// no online max, row-sum via ones-MFMA) + XCD swizzle.
__global__ __launch_bounds__(256) void attn_fwd(
    const bf16_t* __restrict__ Q, const bf16_t* __restrict__ K,
    const bf16_t* __restrict__ Vt, bf16_t* __restrict__ out) {
  __shared__ __align__(16) bf16_t sK[64 * 128];   // 16 KB, swizzled chunks
  __shared__ __align__(16) bf16_t sV[128 * 64];   // 16 KB, swizzled chunks
  __shared__ __align__(16) bf16_t sP[4][32][72];  // 18.4 KB, padded

  const int tid  = threadIdx.x;
  const int lane = tid & 63;
  const int w    = tid >> 6;
  const int lg   = lane >> 4;
  const int lr   = lane & 15;

  const int bid     = blockIdx.x;                 // 0..511
  const int logical = (bid & 7) * 64 + (bid >> 3);
  const int bh      = logical >> 4;               // b*H + h
  const int q0      = (logical & 15) * 128;
  const int qw      = q0 + w * 32;

  const bf16_t* Kb = K  + (size_t)bh * SEQ * HDIM;
  const bf16_t* Vb = Vt + (size_t)bh * HDIM * SEQ;

  bf16x8 qf[2][4];
#pragma unroll
  for (int mf = 0; mf < 2; ++mf) {
    const bf16_t* qbase = Q + ((size_t)bh * SEQ + qw + mf * 16 + lr) * HDIM;
#pragma unroll
    for (int kc = 0; kc < 4; ++kc)
      qf[mf][kc] = *reinterpret_cast<const bf16x8*>(qbase + kc * 32 + lg * 8);
  }

  bf16x8 onesf;
#pragma unroll
  for (int i = 0; i < 8; ++i) onesf[i] = (bf16_t)1.0f;

  f32x4 o[2][8] = {};
  f32x4 o1[2] = {};   // row-sum accumulators

  for (int kv0 = 0; kv0 < SEQ; kv0 += 64) {
    __syncthreads();
#pragma unroll
    for (int p = 0; p < 4; ++p) {
      const int slot = p * 256 + tid;          // 0..1023 (16B chunks)
      const int kr = slot >> 4, kc = slot & 15;
      async_ld16(Kb + ((size_t)(kv0 + kr)) * HDIM + ((kc ^ (kr & 7)) * 8),
                 sK + slot * 8);
      const int vr = slot >> 3, vc = slot & 7;
      async_ld16(Vb + (size_t)vr * SEQ + kv0 + ((vc ^ (vr & 7)) * 8),
                 sV + slot * 8);
    }
    __syncthreads();

    // ---- QK^T
    f32x4 s[2][4] = {};
    __builtin_amdgcn_s_setprio(1);
#pragma unroll
    for (int kc = 0; kc < 4; ++kc) {
#pragma unroll
      for (int cb = 0; cb < 4; ++cb) {
        const int r  = cb * 16 + lr;
        const int ch = kc * 4 + lg;
        bf16x8 kf = *reinterpret_cast<const bf16x8*>(
            sK + r * 128 + ((ch ^ (r & 7)) * 8));
        s[0][cb] = __builtin_amdgcn_mfma_f32_16x16x32_bf16(qf[0][kc], kf, s[0][cb], 0, 0, 0);
        s[1][cb] = __builtin_amdgcn_mfma_f32_16x16x32_bf16(qf[1][kc], kf, s[1][cb], 0, 0, 0);
      }
    }
    __builtin_amdgcn_s_setprio(0);

    // ---- p = exp2(s)
#pragma unroll
    for (int mf = 0; mf < 2; ++mf)
#pragma unroll
      for (int r = 0; r < 4; ++r)
#pragma unroll
        for (int cb = 0; cb < 4; ++cb) {
          const float p = __builtin_amdgcn_exp2f(s[mf][cb][r]);
          sP[w][mf * 16 + lg * 4 + r][cb * 16 + lr] = (bf16_t)p;
        }

    asm volatile("s_waitcnt lgkmcnt(0)" ::: "memory");

    // ---- PV + row-sum
    __builtin_amdgcn_s_setprio(1);
#pragma unroll
    for (int ks = 0; ks < 2; ++ks) {
      bf16x8 pf0 = *reinterpret_cast<const bf16x8*>(&sP[w][lr][ks * 32 + lg * 8]);
      bf16x8 pf1 = *reinterpret_cast<const bf16x8*>(&sP[w][16 + lr][ks * 32 + lg * 8]);
      o1[0] = __builtin_amdgcn_mfma_f32_16x16x32_bf16(pf0, onesf, o1[0], 0, 0, 0);
      o1[1] = __builtin_amdgcn_mfma_f32_16x16x32_bf16(pf1, onesf, o1[1], 0, 0, 0);
#pragma unroll
      for (int ob = 0; ob < 8; ++ob) {
        const int r  = ob * 16 + lr;
        const int ch = ks * 4 + lg;
        bf16x8 vf = *reinterpret_cast<const bf16x8*>(
            sV + r * 64 + ((ch ^ (r & 7)) * 8));
        o[0][ob] = __builtin_amdgcn_mfma_f32_16x16x32_bf16(pf0, vf, o[0][ob], 0, 0, 0);
        o[1][ob] = __builtin_amdgcn_mfma_f32_16x16x32_bf16(pf1, vf, o[1][ob], 0, 0, 0);
      }
    }
    __builtin_amdgcn_s_setprio(0);
  }

  // ---- epilogue
  const int b = bh >> 4, h = bh & 15;
#pragma unroll
  for (int mf = 0; mf < 2; ++mf) {
#pragma unroll
    for (int r = 0; r < 4; ++r) {
      const float inv_l = 1.0f / o1[mf][r];
      const int row = qw + mf * 16 + lg * 4 + r;
      bf16_t* obase = out + ((size_t)b * SEQ + row) * DDIM + h * HDIM;
#pragma unroll
      for (int ob = 0; ob < 8; ++ob)
        obase[ob * 16 + lr] = (bf16_t)(o[mf][ob][r] * inv_l);
    }
  }
}

// ---------------------------------------------------------------- launch
extern "C" void kernel_launch(void* const* d_in, const int* in_sizes, int n_in,
                              void* d_out, int out_size, void* d_ws,
                              size_t ws_size, hipStream_t stream) {
  const float* x  = (const float*)d_in[0];
  const float* Wq = (const float*)d_in[1];
  const float* bq = (const float*)d_in[2];
  const float* Wk = (const float*)d_in[3];
  const float* bk = (const float*)d_in[4];
  const float* Wv = (const float*)d_in[5];
  const float* bv = (const float*)d_in[6];
  const float* Wo = (const float*)d_in[7];
  const float* bo = (const float*)d_in[8];

  bf16_t* ws = (bf16_t*)d_ws;
  const size_t XE = XEL;                   // 8388608
  const size_t WE = (size_t)DDIM * DDIM;   // 4194304
  bf16_t* xb  = ws;          // reused as `merged` after QKV GEMM
  bf16_t* wqb = ws + XE;     // wqb|wkb|wvb contiguous = Wcat [6144][2048]
  bf16_t* wkb = wqb + WE;
  bf16_t* wvb = wkb + WE;
  bf16_t* wob = wvb + WE;
  bf16_t* Qh  = wob + WE;    // Qh|Kh|Vh contiguous
  bf16_t* Kh  = Qh + XE;
  bf16_t* Vh  = Kh + XE;
  bf16_t* Vt  = Vh + XE;
  bf16_t* merged = xb;

  cvt_f32_bf16<<<4096, 256, 0, stream>>>(x, xb, (int)XE);
  cvt_f32_bf16<<<2048, 256, 0, stream>>>(Wq, wqb, (int)WE);
  cvt_f32_bf16<<<2048, 256, 0, stream>>>(Wk, wkb, (int)WE);
  cvt_f32_bf16<<<2048, 256, 0, stream>>>(Wv, wvb, (int)WE);
  cvt_f32_bf16<<<2048, 256, 0, stream>>>(Wo, wob, (int)WE);

  // scale = (1/sqrt(HD)) * log2(e), folded into Q so attn uses exp2 directly
  const float qscale = 0.12751744520778695f;

  gemm_qkv<<<512, 512, 0, stream>>>(xb, wqb, bq, bk, bv, Qh, qscale);

  transpose_v<<<dim3(SEQ / 64, HDIM / 64, BATCH * NH), 256, 0, stream>>>(Vh, Vt);

  attn_fwd<<<512, 256, 0, stream>>>(Qh, Kh, Vt, merged);

  dim3 gg(DDIM / 128, MROWS / 128);
  gemm_bt<2><<<gg, 256, 0, stream>>>(merged, wob, bo, d_out, MROWS, DDIM, DDIM, 1.0f);
}